// Round 5
// baseline (356.067 us; speedup 1.0000x reference)
//
#include <hip/hip_runtime.h>
#include <hip/hip_fp16.h>

// GCN 3->32->32->1, N=100K, E=6.4M (+self loops).
// R9:  L2-resident slice -> FETCH ~compulsory (34.6MB) but issue-bound.
// R10: 4-lane full-row gathers -> low VALU but TLP/coalescing death.
// R11: 8 lanes/node (lane owns 4 feats, 8B gather, no butterfly): 69.7us,
//      VALU 28%, FETCH 190MB -> src-quarter windows phase-drift; now
//      L2-MISS-bound.
// R12: enforce window separation with TWO k_l2 passes over src-halves
//      (split at 50000 -> 3.2MB window, R9-proven resident). csr read once
//      total (each edge in exactly one half). Raw fp32 partials [N][32]
//      round-trip via nontemporal float4 (25.6MB stream). k_sort bins
//      (node x half), emits qmid. Fallback to R11 k_l2 if ws too small.
//      Also k_bsort phase-a replaced by hist-row differencing (scanA
//      prefixes): saves 25.6MB dst re-read + 6.4M LDS atomics.
// R13: fix compile — nontemporal builtins need a clang ext_vector_type,
//      not HIP's float4 class; added fvec4 alias for part-buffer I/O.
// Carried: fp16 g single table, fused k_sort, node-parallel layers,
//      zero global atomics, 256B-aligned carves.

#define BLK 256
#define SB 1280          // chunks; SB*CHUNK == E exactly
#define CHUNK 5000
#define BKT 128          // nodes per bucket
#define NBKT 782         // ceil(100000/128)
#define MAXNB 1024       // scanB width >= NBKT
#define BUFSZ 15360      // k_sort bucket buffer (mean 8192, ~79 sigma)
#define HALF 50000       // src-half split point (window = 50000*64B = 3.2MB)

typedef float fvec4 __attribute__((ext_vector_type(4)));   // clang-native 16B vec

// ---- pass 1: per-chunk histogram over dst buckets (LDS, int4 loads)
__global__ void k_hist(const int* __restrict__ dst, int* __restrict__ hist, int E) {
    __shared__ int lh[NBKT];
    for (int b = threadIdx.x; b < NBKT; b += blockDim.x) lh[b] = 0;
    __syncthreads();
    int beg = blockIdx.x * CHUNK;
    int end = min(E, beg + CHUNK);
    int nq = (end - beg) >> 2;                    // full int4 quads
    const int4* d4 = (const int4*)(dst + beg);
    for (int i = threadIdx.x; i < nq; i += blockDim.x) {
        int4 d = d4[i];
        atomicAdd(&lh[d.x >> 7], 1);
        atomicAdd(&lh[d.y >> 7], 1);
        atomicAdd(&lh[d.z >> 7], 1);
        atomicAdd(&lh[d.w >> 7], 1);
    }
    for (int e = beg + (nq << 2) + threadIdx.x; e < end; e += blockDim.x)
        atomicAdd(&lh[dst[e] >> 7], 1);
    __syncthreads();
    for (int b = threadIdx.x; b < NBKT; b += blockDim.x)
        hist[(size_t)blockIdx.x * NBKT + b] = lh[b];
}

// ---- scan A: per bucket, exclusive-scan its SB chunk-counts (shfl, 5 items/thr)
__global__ void k_scanA(int* __restrict__ hist, int* __restrict__ btot, int NB) {
    int b = blockIdx.x, t = threadIdx.x;          // 256 threads * 5 items = 1280
    int base = t * 5;
    int v0 = hist[(size_t)(base + 0) * NB + b];
    int v1 = hist[(size_t)(base + 1) * NB + b];
    int v2 = hist[(size_t)(base + 2) * NB + b];
    int v3 = hist[(size_t)(base + 3) * NB + b];
    int v4 = hist[(size_t)(base + 4) * NB + b];
    int s = v0 + v1 + v2 + v3 + v4;
    int lane = t & 63, w = t >> 6;
    int x = s;
#pragma unroll
    for (int off = 1; off < 64; off <<= 1) {
        int u = __shfl_up(x, off, 64);
        if (lane >= off) x += u;
    }
    __shared__ int wsum[4];
    if (lane == 63) wsum[w] = x;
    __syncthreads();
    int woff = 0;
    for (int k = 0; k < 4; k++) woff += (k < w) ? wsum[k] : 0;
    int run = woff + x - s;                       // exclusive prefix for item 0
    hist[(size_t)(base + 0) * NB + b] = run;  run += v0;
    hist[(size_t)(base + 1) * NB + b] = run;  run += v1;
    hist[(size_t)(base + 2) * NB + b] = run;  run += v2;
    hist[(size_t)(base + 3) * NB + b] = run;  run += v3;
    hist[(size_t)(base + 4) * NB + b] = run;  run += v4;
    if (t == 255) btot[b] = run;
}

// ---- scan B: exclusive-scan bucket totals -> bucket base offsets
__global__ void k_scanB(const int* __restrict__ btot, int* __restrict__ bbase,
                        int NB, int E) {
    __shared__ int sh[MAXNB];
    int t = threadIdx.x;
    int v = (t < NB) ? btot[t] : 0;
    sh[t] = v;
    __syncthreads();
    for (int off = 1; off < MAXNB; off <<= 1) {
        int u = (t >= off) ? sh[t - off] : 0;
        __syncthreads();
        sh[t] += u;
        __syncthreads();
    }
    if (t < NB) bbase[t] = sh[t] - v;
    if (t == 0) bbase[NB] = E;
}

// ---- pass 2: LDS chunk-sort by bucket, full-lane sorted-order streaming.
// Chunk counts come from hist-row differencing (scanA in-place prefixes):
// cnt[c][b] = hist[c+1][b] - hist[c][b]  (btot[b] caps the last chunk).
__global__ void k_bsort(const int* __restrict__ src, const int* __restrict__ dst,
                        const int* __restrict__ hist, const int* __restrict__ btot,
                        const int* __restrict__ bbase,
                        unsigned int* __restrict__ packed, int E) {
    __shared__ unsigned int bufB[CHUNK];          // 20 KB
    __shared__ unsigned short binarr2[CHUNK];     // 10 KB (bucket of sorted pos)
    __shared__ int cnt[NBKT];
    __shared__ int off[NBKT];
    __shared__ int cur[NBKT];
    __shared__ int gbase[NBKT];
    __shared__ int wsum[4];
    int t = threadIdx.x;
    int beg = blockIdx.x * CHUNK;
    int end = min(E, beg + CHUNK);
    int len = end - beg;
    int last = (blockIdx.x + 1 == gridDim.x);
    for (int b = t; b < NBKT; b += blockDim.x) {
        int my = hist[(size_t)blockIdx.x * NBKT + b];
        int nx = last ? btot[b] : hist[(size_t)(blockIdx.x + 1) * NBKT + b];
        cnt[b] = nx - my;
        gbase[b] = bbase[b] + my;
    }
    __syncthreads();
    // phase b: exclusive scan of 782 counts (4 items/thread, shfl)
    {
        int base = t * 4;
        int v0 = (base + 0 < NBKT) ? cnt[base + 0] : 0;
        int v1 = (base + 1 < NBKT) ? cnt[base + 1] : 0;
        int v2 = (base + 2 < NBKT) ? cnt[base + 2] : 0;
        int v3 = (base + 3 < NBKT) ? cnt[base + 3] : 0;
        int s = v0 + v1 + v2 + v3;
        int lane = t & 63, w = t >> 6;
        int x = s;
#pragma unroll
        for (int o = 1; o < 64; o <<= 1) {
            int u = __shfl_up(x, o, 64);
            if (lane >= o) x += u;
        }
        if (lane == 63) wsum[w] = x;
        __syncthreads();
        int woff = 0;
        for (int k = 0; k < 4; k++) woff += (k < w) ? wsum[k] : 0;
        int run = woff + x - s;
        if (base + 0 < NBKT) { off[base + 0] = run; cur[base + 0] = run; } run += v0;
        if (base + 1 < NBKT) { off[base + 1] = run; cur[base + 1] = run; } run += v1;
        if (base + 2 < NBKT) { off[base + 2] = run; cur[base + 2] = run; } run += v2;
        if (base + 3 < NBKT) { off[base + 3] = run; cur[base + 3] = run; } run += v3;
    }
    __syncthreads();
    // phase c: permute into bucket-grouped order
    for (int i = t; i < len; i += blockDim.x) {
        int d = dst[beg + i];
        int s = src[beg + i];
        int b = d >> 7;
        int pos = atomicAdd(&cur[b], 1);
        bufB[pos] = (unsigned)s | ((unsigned)(d & 127) << 17);
        binarr2[pos] = (unsigned short)b;
    }
    __syncthreads();
    // phase d: full-lane sorted-order write (runs are dest-contiguous)
    for (int i = t; i < len; i += blockDim.x) {
        int b = binarr2[i];
        packed[gbase[b] + i - off[b]] = bufB[i];
    }
}

// ---- fused: per-bucket 256-bin count (node x src-half) + scan +
// dis/y4/rowptr/qmid + in-place sort: node-major, src-half-minor order.
__global__ void k_sort(unsigned int* __restrict__ packed, const int* __restrict__ bbase,
                       const float* __restrict__ x, float* __restrict__ dis,
                       float4* __restrict__ y4, int* __restrict__ rowptr,
                       int* __restrict__ qmid, int N, int E) {
    __shared__ unsigned int buf[BUFSZ];
    __shared__ int cnt[2 * BKT];                  // 256 bins
    __shared__ int cur[2 * BKT];
    __shared__ int wsum[4];
    int b = blockIdx.x, t = threadIdx.x;
    int beg = bbase[b], end = bbase[b + 1];
    int len = end - beg;
    for (int i = t; i < len; i += blockDim.x) buf[i] = packed[beg + i];
    cnt[t] = 0;
    __syncthreads();
    for (int i = t; i < len; i += blockDim.x) {
        unsigned v = buf[i];
        int s = (int)(v & 0x1FFFFu);
        int key = (int)((v >> 17) << 1) | (s >= HALF);
        atomicAdd(&cnt[key], 1);
    }
    __syncthreads();
    // exclusive scan over 256 bins, 1 item/thread (shfl + wave sums)
    {
        int v0 = cnt[t];
        int lane = t & 63, w = t >> 6;
        int xs = v0;
#pragma unroll
        for (int o = 1; o < 64; o <<= 1) {
            int u = __shfl_up(xs, o, 64);
            if (lane >= o) xs += u;
        }
        if (lane == 63) wsum[w] = xs;
        __syncthreads();
        int woff = 0;
        for (int k = 0; k < 4; k++) woff += (k < w) ? wsum[k] : 0;
        cur[t] = woff + xs - v0;
    }
    __syncthreads();
    if (t < BKT) {
        int excl = cur[2 * t];                    // node segment start
        int v = cnt[2 * t] + cnt[2 * t + 1];
        int gi = b * BKT + t;
        if (gi < N) {
            rowptr[gi] = beg + excl;
            qmid[gi]   = beg + cur[2 * t + 1];    // start of src-half-1 edges
            float di = rsqrtf((float)v + 1.0f);   // + self loop
            dis[gi] = di;
            float4 y;
            y.x = di * x[3 * gi + 0];
            y.y = di * x[3 * gi + 1];
            y.z = di * x[3 * gi + 2];
            y.w = 0.0f;
            y4[gi] = y;
        }
    }
    __syncthreads();
    for (int i = t; i < len; i += blockDim.x) {
        unsigned vv = buf[i];
        int s = (int)(vv & 0x1FFFFu);
        int key = (int)((vv >> 17) << 1) | (s >= HALF);
        int pos = atomicAdd(&cur[key], 1);        // LDS atomic
        packed[beg + pos] = (unsigned)s;          // plain src id
    }
    if (b == 0 && t == 0) rowptr[N] = E;
}

// ---- layer 1: node-parallel, 32 lanes/node gather y4 (1.6MB, L2-resident)
__global__ void k_l1(const unsigned int* __restrict__ csr, const int* __restrict__ rowptr,
                     const float4* __restrict__ y4, const float* __restrict__ dis,
                     const float* __restrict__ W1, const float* __restrict__ b1,
                     __half* __restrict__ g, int N) {
    int t = blockIdx.x * blockDim.x + threadIdx.x;
    int i = t >> 5, j = t & 31;
    if (i >= N) return;
    int beg = rowptr[i], end = rowptr[i + 1];
    float ax = 0.f, ay = 0.f, az = 0.f;
    for (int e = beg + j; e < end; e += 32) {
        float4 yv = y4[csr[e]];
        ax += yv.x; ay += yv.y; az += yv.z;
    }
#pragma unroll
    for (int m = 16; m >= 1; m >>= 1) {
        ax += __shfl_xor(ax, m, 32);
        ay += __shfl_xor(ay, m, 32);
        az += __shfl_xor(az, m, 32);
    }
    float di = dis[i];
    float4 ys = y4[i];                               // self loop (pre-scaled)
    float a0 = di * (ax + ys.x);
    float a1 = di * (ay + ys.y);
    float a2 = di * (az + ys.z);
    float h = b1[j] + a0 * W1[j] + a1 * W1[32 + j] + a2 * W1[64 + j];
    g[(size_t)i * 32 + j] = __float2half(di * fmaxf(h, 0.f));
}

// unpack one uint2 (4 halves) and accumulate into 4 fp32 accumulators
__device__ __forceinline__ void acc4(float& c0, float& c1, float& c2, float& c3,
                                     uint2 r) {
    __half2 a = *(const __half2*)&r.x;
    __half2 b = *(const __half2*)&r.y;
    float2 fa = __half22float2(a);
    float2 fb = __half22float2(b);
    c0 += fa.x; c1 += fa.y; c2 += fb.x; c3 += fb.y;
}

// shared gather core: accumulate g rows over edge range [beg,end)
__device__ __forceinline__ void gath(const unsigned int* __restrict__ csr,
                                     const uint2* __restrict__ g2, int j,
                                     int beg, int end,
                                     float& c0, float& c1, float& c2, float& c3) {
    int e = beg;
    for (; e + 8 <= end; e += 8) {
        int s0 = (int)csr[e + 0], s1 = (int)csr[e + 1];
        int s2 = (int)csr[e + 2], s3 = (int)csr[e + 3];
        int s4 = (int)csr[e + 4], s5 = (int)csr[e + 5];
        int s6 = (int)csr[e + 6], s7 = (int)csr[e + 7];
        uint2 r0 = g2[s0 * 8 + j];
        uint2 r1 = g2[s1 * 8 + j];
        uint2 r2 = g2[s2 * 8 + j];
        uint2 r3 = g2[s3 * 8 + j];
        uint2 r4 = g2[s4 * 8 + j];
        uint2 r5 = g2[s5 * 8 + j];
        uint2 r6 = g2[s6 * 8 + j];
        uint2 r7 = g2[s7 * 8 + j];
        acc4(c0, c1, c2, c3, r0);
        acc4(c0, c1, c2, c3, r1);
        acc4(c0, c1, c2, c3, r2);
        acc4(c0, c1, c2, c3, r3);
        acc4(c0, c1, c2, c3, r4);
        acc4(c0, c1, c2, c3, r5);
        acc4(c0, c1, c2, c3, r6);
        acc4(c0, c1, c2, c3, r7);
    }
    for (; e < end; e++) {
        int s = (int)csr[e];
        uint2 r = g2[s * 8 + j];
        acc4(c0, c1, c2, c3, r);
    }
}

// ---- layer 2 pass A: gather src-half-0 edges only (3.2MB window, L2-resident);
// write raw fp32 partial sums, nontemporal (pure stream, keep L2 for the window)
__global__ void k_l2a(const unsigned int* __restrict__ csr, const int* __restrict__ rowptr,
                      const int* __restrict__ qmid, const __half* __restrict__ g,
                      fvec4* __restrict__ part4, int N) {
    int t = blockIdx.x * blockDim.x + threadIdx.x;
    int i = t >> 3, j = t & 7;
    if (i >= N) return;
    float c0 = 0.f, c1 = 0.f, c2 = 0.f, c3 = 0.f;
    gath(csr, (const uint2*)g, j, rowptr[i], qmid[i], c0, c1, c2, c3);
    fvec4 p = {c0, c1, c2, c3};
    __builtin_nontemporal_store(p, &part4[(size_t)i * 8 + j]);
}

// ---- layer 2 pass B: gather src-half-1 edges, add partials + self row,
// di scale, W2/W3 epilogue (lane j -> outputs 4j..4j+3), q write.
__global__ void k_l2b(const unsigned int* __restrict__ csr, const int* __restrict__ rowptr,
                      const int* __restrict__ qmid, const __half* __restrict__ g,
                      const float* __restrict__ dis, const fvec4* __restrict__ part4,
                      const float* __restrict__ W2, const float* __restrict__ b2,
                      const float* __restrict__ W3, float* __restrict__ q, int N) {
    int t = blockIdx.x * blockDim.x + threadIdx.x;
    int i = t >> 3, j = t & 7;
    if (i >= N) return;
    const uint2* g2 = (const uint2*)g;
    float c0 = 0.f, c1 = 0.f, c2 = 0.f, c3 = 0.f;
    gath(csr, g2, j, qmid[i], rowptr[i + 1], c0, c1, c2, c3);
    fvec4 p = __builtin_nontemporal_load(&part4[(size_t)i * 8 + j]);
    c0 += p.x; c1 += p.y; c2 += p.z; c3 += p.w;
    float di = dis[i];
    uint2 rs = g2[i * 8 + j];                        // self-loop slice
    float2 sa = __half22float2(*(const __half2*)&rs.x);
    float2 sb = __half22float2(*(const __half2*)&rs.y);
    float a0 = di * (c0 + sa.x);
    float a1 = di * (c1 + sa.y);
    float a2 = di * (c2 + sb.x);
    float a3 = di * (c3 + sb.y);
    int m = 4 * j;
    float o0 = b2[m + 0], o1 = b2[m + 1], o2 = b2[m + 2], o3 = b2[m + 3];
#pragma unroll
    for (int kl = 0; kl < 8; kl++) {
        float x0 = __shfl(a0, kl, 8);                // a[4kl+0]
        float x1 = __shfl(a1, kl, 8);
        float x2 = __shfl(a2, kl, 8);
        float x3 = __shfl(a3, kl, 8);
        const float* w0 = W2 + (4 * kl) * 32 + m;    // rows 4kl..4kl+3, cols m..m+3
        o0 = fmaf(x0, w0[0], fmaf(x1, w0[32], fmaf(x2, w0[64], fmaf(x3, w0[96], o0))));
        o1 = fmaf(x0, w0[1], fmaf(x1, w0[33], fmaf(x2, w0[65], fmaf(x3, w0[97], o1))));
        o2 = fmaf(x0, w0[2], fmaf(x1, w0[34], fmaf(x2, w0[66], fmaf(x3, w0[98], o2))));
        o3 = fmaf(x0, w0[3], fmaf(x1, w0[35], fmaf(x2, w0[67], fmaf(x3, w0[99], o3))));
    }
    float cc = fmaxf(o0, 0.f) * W3[m + 0] + fmaxf(o1, 0.f) * W3[m + 1]
             + fmaxf(o2, 0.f) * W3[m + 2] + fmaxf(o3, 0.f) * W3[m + 3];
    cc += __shfl_xor(cc, 1, 8);
    cc += __shfl_xor(cc, 2, 8);
    cc += __shfl_xor(cc, 4, 8);
    if (j == 0) q[i] = di * cc;                      // q = dis * p
}

// ---- fallback single-pass layer 2 (R11) if ws can't hold part/qmid
__global__ void k_l2f(const unsigned int* __restrict__ csr, const int* __restrict__ rowptr,
                      const __half* __restrict__ g, const float* __restrict__ dis,
                      const float* __restrict__ W2, const float* __restrict__ b2,
                      const float* __restrict__ W3, float* __restrict__ q, int N) {
    int t = blockIdx.x * blockDim.x + threadIdx.x;
    int i = t >> 3, j = t & 7;
    if (i >= N) return;
    const uint2* g2 = (const uint2*)g;
    float c0 = 0.f, c1 = 0.f, c2 = 0.f, c3 = 0.f;
    gath(csr, g2, j, rowptr[i], rowptr[i + 1], c0, c1, c2, c3);
    float di = dis[i];
    uint2 rs = g2[i * 8 + j];
    float2 sa = __half22float2(*(const __half2*)&rs.x);
    float2 sb = __half22float2(*(const __half2*)&rs.y);
    float a0 = di * (c0 + sa.x);
    float a1 = di * (c1 + sa.y);
    float a2 = di * (c2 + sb.x);
    float a3 = di * (c3 + sb.y);
    int m = 4 * j;
    float o0 = b2[m + 0], o1 = b2[m + 1], o2 = b2[m + 2], o3 = b2[m + 3];
#pragma unroll
    for (int kl = 0; kl < 8; kl++) {
        float x0 = __shfl(a0, kl, 8);
        float x1 = __shfl(a1, kl, 8);
        float x2 = __shfl(a2, kl, 8);
        float x3 = __shfl(a3, kl, 8);
        const float* w0 = W2 + (4 * kl) * 32 + m;
        o0 = fmaf(x0, w0[0], fmaf(x1, w0[32], fmaf(x2, w0[64], fmaf(x3, w0[96], o0))));
        o1 = fmaf(x0, w0[1], fmaf(x1, w0[33], fmaf(x2, w0[65], fmaf(x3, w0[97], o1))));
        o2 = fmaf(x0, w0[2], fmaf(x1, w0[34], fmaf(x2, w0[66], fmaf(x3, w0[98], o2))));
        o3 = fmaf(x0, w0[3], fmaf(x1, w0[35], fmaf(x2, w0[67], fmaf(x3, w0[99], o3))));
    }
    float cc = fmaxf(o0, 0.f) * W3[m + 0] + fmaxf(o1, 0.f) * W3[m + 1]
             + fmaxf(o2, 0.f) * W3[m + 2] + fmaxf(o3, 0.f) * W3[m + 3];
    cc += __shfl_xor(cc, 1, 8);
    cc += __shfl_xor(cc, 2, 8);
    cc += __shfl_xor(cc, 4, 8);
    if (j == 0) q[i] = di * cc;
}

// ---- layer 3: node-parallel scalar q gathers (q 400KB, L2-resident)
__global__ void k_l3(const unsigned int* __restrict__ csr, const int* __restrict__ rowptr,
                     const float* __restrict__ q, const float* __restrict__ dis,
                     const float* __restrict__ b3, float* __restrict__ out, int N) {
    int t = blockIdx.x * blockDim.x + threadIdx.x;
    int i = t >> 5, j = t & 31;
    if (i >= N) return;
    int beg = rowptr[i], end = rowptr[i + 1];
    float acc = 0.f;
    for (int e = beg + j; e < end; e += 32)
        acc += q[csr[e]];
#pragma unroll
    for (int m = 16; m >= 1; m >>= 1)
        acc += __shfl_xor(acc, m, 32);
    if (j == 0) out[i] = dis[i] * (acc + q[i]) + b3[0];
}

extern "C" void kernel_launch(void* const* d_in, const int* in_sizes, int n_in,
                              void* d_out, int out_size, void* d_ws, size_t ws_size,
                              hipStream_t stream) {
    const float* x  = (const float*)d_in[0];
    const int*   ei = (const int*)d_in[1];
    const float* W1 = (const float*)d_in[2];
    const float* b1 = (const float*)d_in[3];
    const float* W2 = (const float*)d_in[4];
    const float* b2 = (const float*)d_in[5];
    const float* W3 = (const float*)d_in[6];
    const float* b3 = (const float*)d_in[7];
    float* out = (float*)d_out;

    int N = in_sizes[0] / 3;
    int E = in_sizes[1] / 2;
    const int* src = ei;
    const int* dst = ei + E;

    // workspace (all init done in-kernel; no memset needed), 256B-aligned carves
    char* w = (char*)d_ws;
#define CARVE(nbytes) w; w += (((size_t)(nbytes) + 255) & ~(size_t)255)
    int*   hist   = (int*)  CARVE((size_t)SB * NBKT * 4);   // 4.0 MB
    int*   btot   = (int*)  CARVE((size_t)MAXNB * 4);
    int*   bbase  = (int*)  CARVE((size_t)(MAXNB + 1) * 4);
    int*   rowptr = (int*)  CARVE((size_t)(N + 1) * 4);
    float* dis    = (float*)CARVE((size_t)N * 4);
    float* y4     = (float*)CARVE((size_t)N * 16);
    __half* g     = (__half*)CARVE((size_t)N * 32 * 2);     // 6.4 MB fp16
    float* q      = (float*)CARVE((size_t)N * 4);
    unsigned int* packed = (unsigned int*)CARVE((size_t)E * 4);  // 25.6 MB
    int*   qmid   = (int*)  CARVE((size_t)N * 4);           // split path only
    fvec4* part4  = (fvec4*)CARVE((size_t)N * 32 * 4);      // 12.8 MB, split only
    size_t need_split = (size_t)(w - (char*)d_ws);
#undef CARVE
    int use_split = (ws_size >= need_split);
    if (!use_split) qmid = hist;                  // hist dead after k_bsort; k_sort
                                                  // still needs a valid sink (0.4MB)

    k_hist <<<SB, BLK, 0, stream>>>(dst, hist, E);
    k_scanA<<<NBKT, BLK, 0, stream>>>(hist, btot, NBKT);
    k_scanB<<<1, MAXNB, 0, stream>>>(btot, bbase, NBKT, E);
    k_bsort<<<SB, BLK, 0, stream>>>(src, dst, hist, btot, bbase, packed, E);
    k_sort <<<NBKT, BLK, 0, stream>>>(packed, bbase, x, dis, (float4*)y4, rowptr,
                                      qmid, N, E);

    long long tn = (long long)N * 32;
    unsigned gn = (unsigned)((tn + BLK - 1) / BLK);
    long long tn8 = (long long)N * 8;
    unsigned gn8 = (unsigned)((tn8 + BLK - 1) / BLK);
    k_l1<<<gn, BLK, 0, stream>>>(packed, rowptr, (const float4*)y4, dis, W1, b1, g, N);
    if (use_split) {
        k_l2a<<<gn8, BLK, 0, stream>>>(packed, rowptr, qmid, g, part4, N);
        k_l2b<<<gn8, BLK, 0, stream>>>(packed, rowptr, qmid, g, dis, part4,
                                       W2, b2, W3, q, N);
    } else {
        k_l2f<<<gn8, BLK, 0, stream>>>(packed, rowptr, g, dis, W2, b2, W3, q, N);
    }
    k_l3<<<gn, BLK, 0, stream>>>(packed, rowptr, q, dis, b3, out, N);
}

// Round 6
// 336.759 us; speedup vs baseline: 1.0573x; 1.0573x over previous
//
#include <hip/hip_runtime.h>
#include <hip/hip_fp16.h>

// GCN 3->32->32->1, N=100K, E=6.4M (+self loops).
// R11: 8-lane/node k_l2 (69.7us). R12/R13: two k_l2 passes over src-halves
//   (3.2MB L2-resident window), fp32 part round-trip; k_bsort phase-a
//   replaced by hist-row differencing. Total 356; k_l2a/b now <56us each.
// R14: profile flipped — k_sort (56.4us, occ 14.6%, VALU 7%) and k_bsort
//   (56.8us, occ 18%) are wave-starved latency chains, not BW-bound.
//   (a) k_sort: BUFSZ 15360->10240 (40KB; binomial mean 8192, sigma~90,
//       +22sigma safe) -> 3 blocks/CU; 512-thread blocks -> 24 waves/CU
//       (was 8); fused load+count (one fewer barrier/pass).
//   (b) k_bsort: 512-thread blocks (scan: 2 items/thr, wsum[8]) -> serial
//       phase length halves, 24 waves/CU.
// Carried: fp16 g table, l2 split w/ fallback, node-parallel layers,
//   zero global atomics, 256B-aligned carves.

#define BLK 256
#define BLK2 512         // k_bsort / k_sort block size
#define SB 1280          // chunks; SB*CHUNK == E exactly
#define CHUNK 5000
#define BKT 128          // nodes per bucket
#define NBKT 782         // ceil(100000/128)
#define MAXNB 1024       // scanB width >= NBKT
#define BUFSZ 10240      // k_sort bucket buffer (mean 8192 + 22 sigma)
#define HALF 50000       // src-half split point (window = 50000*64B = 3.2MB)

typedef float fvec4 __attribute__((ext_vector_type(4)));   // clang-native 16B vec

// ---- pass 1: per-chunk histogram over dst buckets (LDS, int4 loads)
__global__ void k_hist(const int* __restrict__ dst, int* __restrict__ hist, int E) {
    __shared__ int lh[NBKT];
    for (int b = threadIdx.x; b < NBKT; b += blockDim.x) lh[b] = 0;
    __syncthreads();
    int beg = blockIdx.x * CHUNK;
    int end = min(E, beg + CHUNK);
    int nq = (end - beg) >> 2;                    // full int4 quads
    const int4* d4 = (const int4*)(dst + beg);
    for (int i = threadIdx.x; i < nq; i += blockDim.x) {
        int4 d = d4[i];
        atomicAdd(&lh[d.x >> 7], 1);
        atomicAdd(&lh[d.y >> 7], 1);
        atomicAdd(&lh[d.z >> 7], 1);
        atomicAdd(&lh[d.w >> 7], 1);
    }
    for (int e = beg + (nq << 2) + threadIdx.x; e < end; e += blockDim.x)
        atomicAdd(&lh[dst[e] >> 7], 1);
    __syncthreads();
    for (int b = threadIdx.x; b < NBKT; b += blockDim.x)
        hist[(size_t)blockIdx.x * NBKT + b] = lh[b];
}

// ---- scan A: per bucket, exclusive-scan its SB chunk-counts (shfl, 5 items/thr)
__global__ void k_scanA(int* __restrict__ hist, int* __restrict__ btot, int NB) {
    int b = blockIdx.x, t = threadIdx.x;          // 256 threads * 5 items = 1280
    int base = t * 5;
    int v0 = hist[(size_t)(base + 0) * NB + b];
    int v1 = hist[(size_t)(base + 1) * NB + b];
    int v2 = hist[(size_t)(base + 2) * NB + b];
    int v3 = hist[(size_t)(base + 3) * NB + b];
    int v4 = hist[(size_t)(base + 4) * NB + b];
    int s = v0 + v1 + v2 + v3 + v4;
    int lane = t & 63, w = t >> 6;
    int x = s;
#pragma unroll
    for (int off = 1; off < 64; off <<= 1) {
        int u = __shfl_up(x, off, 64);
        if (lane >= off) x += u;
    }
    __shared__ int wsum[4];
    if (lane == 63) wsum[w] = x;
    __syncthreads();
    int woff = 0;
    for (int k = 0; k < 4; k++) woff += (k < w) ? wsum[k] : 0;
    int run = woff + x - s;                       // exclusive prefix for item 0
    hist[(size_t)(base + 0) * NB + b] = run;  run += v0;
    hist[(size_t)(base + 1) * NB + b] = run;  run += v1;
    hist[(size_t)(base + 2) * NB + b] = run;  run += v2;
    hist[(size_t)(base + 3) * NB + b] = run;  run += v3;
    hist[(size_t)(base + 4) * NB + b] = run;  run += v4;
    if (t == 255) btot[b] = run;
}

// ---- scan B: exclusive-scan bucket totals -> bucket base offsets
__global__ void k_scanB(const int* __restrict__ btot, int* __restrict__ bbase,
                        int NB, int E) {
    __shared__ int sh[MAXNB];
    int t = threadIdx.x;
    int v = (t < NB) ? btot[t] : 0;
    sh[t] = v;
    __syncthreads();
    for (int off = 1; off < MAXNB; off <<= 1) {
        int u = (t >= off) ? sh[t - off] : 0;
        __syncthreads();
        sh[t] += u;
        __syncthreads();
    }
    if (t < NB) bbase[t] = sh[t] - v;
    if (t == 0) bbase[NB] = E;
}

// ---- pass 2: LDS chunk-sort by bucket, full-lane sorted-order streaming.
// Chunk counts from hist-row differencing (scanA in-place prefixes).
// 512 threads: scan is 2 items/thread over 8 waves.
__global__ void k_bsort(const int* __restrict__ src, const int* __restrict__ dst,
                        const int* __restrict__ hist, const int* __restrict__ btot,
                        const int* __restrict__ bbase,
                        unsigned int* __restrict__ packed, int E) {
    __shared__ unsigned int bufB[CHUNK];          // 20 KB
    __shared__ unsigned short binarr2[CHUNK];     // 10 KB (bucket of sorted pos)
    __shared__ int cnt[NBKT];
    __shared__ int off[NBKT];
    __shared__ int cur[NBKT];
    __shared__ int gbase[NBKT];
    __shared__ int wsum[8];
    int t = threadIdx.x;
    int beg = blockIdx.x * CHUNK;
    int end = min(E, beg + CHUNK);
    int len = end - beg;
    int last = (blockIdx.x + 1 == gridDim.x);
    for (int b = t; b < NBKT; b += blockDim.x) {
        int my = hist[(size_t)blockIdx.x * NBKT + b];
        int nx = last ? btot[b] : hist[(size_t)(blockIdx.x + 1) * NBKT + b];
        cnt[b] = nx - my;
        gbase[b] = bbase[b] + my;
    }
    __syncthreads();
    // phase b: exclusive scan of 782 counts (2 items/thread, shfl, 8 waves)
    {
        int base = t * 2;
        int v0 = (base + 0 < NBKT) ? cnt[base + 0] : 0;
        int v1 = (base + 1 < NBKT) ? cnt[base + 1] : 0;
        int s = v0 + v1;
        int lane = t & 63, w = t >> 6;
        int x = s;
#pragma unroll
        for (int o = 1; o < 64; o <<= 1) {
            int u = __shfl_up(x, o, 64);
            if (lane >= o) x += u;
        }
        if (lane == 63) wsum[w] = x;
        __syncthreads();
        int woff = 0;
        for (int k = 0; k < 8; k++) woff += (k < w) ? wsum[k] : 0;
        int run = woff + x - s;
        if (base + 0 < NBKT) { off[base + 0] = run; cur[base + 0] = run; } run += v0;
        if (base + 1 < NBKT) { off[base + 1] = run; cur[base + 1] = run; } run += v1;
    }
    __syncthreads();
    // phase c: permute into bucket-grouped order
    for (int i = t; i < len; i += blockDim.x) {
        int d = dst[beg + i];
        int s = src[beg + i];
        int b = d >> 7;
        int pos = atomicAdd(&cur[b], 1);
        bufB[pos] = (unsigned)s | ((unsigned)(d & 127) << 17);
        binarr2[pos] = (unsigned short)b;
    }
    __syncthreads();
    // phase d: full-lane sorted-order write (runs are dest-contiguous)
    for (int i = t; i < len; i += blockDim.x) {
        int b = binarr2[i];
        packed[gbase[b] + i - off[b]] = bufB[i];
    }
}

// ---- fused: per-bucket 256-bin count (node x src-half) + scan +
// dis/y4/rowptr/qmid + in-place sort. 512 threads, fused load+count.
__global__ void k_sort(unsigned int* __restrict__ packed, const int* __restrict__ bbase,
                       const float* __restrict__ x, float* __restrict__ dis,
                       float4* __restrict__ y4, int* __restrict__ rowptr,
                       int* __restrict__ qmid, int N, int E) {
    __shared__ unsigned int buf[BUFSZ];           // 40 KB
    __shared__ int cnt[2 * BKT];                  // 256 bins
    __shared__ int cur[2 * BKT];
    __shared__ int wsum[4];
    int b = blockIdx.x, t = threadIdx.x;
    int beg = bbase[b], end = bbase[b + 1];
    int len = end - beg;
    if (t < 2 * BKT) cnt[t] = 0;
    __syncthreads();
    // fused: load bucket into LDS + count bins in one pass
    for (int i = t; i < len; i += blockDim.x) {
        unsigned v = packed[beg + i];
        buf[i] = v;
        int s = (int)(v & 0x1FFFFu);
        int key = (int)((v >> 17) << 1) | (s >= HALF);
        atomicAdd(&cnt[key], 1);
    }
    __syncthreads();
    // exclusive scan over 256 bins (threads 0..255, waves 0..3 fully active)
    int v0 = 0, xs = 0;
    if (t < 2 * BKT) {
        v0 = cnt[t];
        xs = v0;
#pragma unroll
        for (int o = 1; o < 64; o <<= 1) {
            int u = __shfl_up(xs, o, 64);
            if ((t & 63) >= o) xs += u;
        }
        if ((t & 63) == 63) wsum[t >> 6] = xs;
    }
    __syncthreads();
    if (t < 2 * BKT) {
        int woff = 0;
        for (int k = 0; k < 4; k++) woff += (k < (t >> 6)) ? wsum[k] : 0;
        cur[t] = woff + xs - v0;
    }
    __syncthreads();
    if (t < BKT) {
        int excl = cur[2 * t];                    // node segment start
        int v = cnt[2 * t] + cnt[2 * t + 1];
        int gi = b * BKT + t;
        if (gi < N) {
            rowptr[gi] = beg + excl;
            qmid[gi]   = beg + cur[2 * t + 1];    // start of src-half-1 edges
            float di = rsqrtf((float)v + 1.0f);   // + self loop
            dis[gi] = di;
            float4 y;
            y.x = di * x[3 * gi + 0];
            y.y = di * x[3 * gi + 1];
            y.z = di * x[3 * gi + 2];
            y.w = 0.0f;
            y4[gi] = y;
        }
    }
    __syncthreads();
    for (int i = t; i < len; i += blockDim.x) {
        unsigned vv = buf[i];
        int s = (int)(vv & 0x1FFFFu);
        int key = (int)((vv >> 17) << 1) | (s >= HALF);
        int pos = atomicAdd(&cur[key], 1);        // LDS atomic
        packed[beg + pos] = (unsigned)s;          // plain src id
    }
    if (b == 0 && t == 0) rowptr[N] = E;
}

// ---- layer 1: node-parallel, 32 lanes/node gather y4 (1.6MB, L2-resident)
__global__ void k_l1(const unsigned int* __restrict__ csr, const int* __restrict__ rowptr,
                     const float4* __restrict__ y4, const float* __restrict__ dis,
                     const float* __restrict__ W1, const float* __restrict__ b1,
                     __half* __restrict__ g, int N) {
    int t = blockIdx.x * blockDim.x + threadIdx.x;
    int i = t >> 5, j = t & 31;
    if (i >= N) return;
    int beg = rowptr[i], end = rowptr[i + 1];
    float ax = 0.f, ay = 0.f, az = 0.f;
    for (int e = beg + j; e < end; e += 32) {
        float4 yv = y4[csr[e]];
        ax += yv.x; ay += yv.y; az += yv.z;
    }
#pragma unroll
    for (int m = 16; m >= 1; m >>= 1) {
        ax += __shfl_xor(ax, m, 32);
        ay += __shfl_xor(ay, m, 32);
        az += __shfl_xor(az, m, 32);
    }
    float di = dis[i];
    float4 ys = y4[i];                               // self loop (pre-scaled)
    float a0 = di * (ax + ys.x);
    float a1 = di * (ay + ys.y);
    float a2 = di * (az + ys.z);
    float h = b1[j] + a0 * W1[j] + a1 * W1[32 + j] + a2 * W1[64 + j];
    g[(size_t)i * 32 + j] = __float2half(di * fmaxf(h, 0.f));
}

// unpack one uint2 (4 halves) and accumulate into 4 fp32 accumulators
__device__ __forceinline__ void acc4(float& c0, float& c1, float& c2, float& c3,
                                     uint2 r) {
    __half2 a = *(const __half2*)&r.x;
    __half2 b = *(const __half2*)&r.y;
    float2 fa = __half22float2(a);
    float2 fb = __half22float2(b);
    c0 += fa.x; c1 += fa.y; c2 += fb.x; c3 += fb.y;
}

// shared gather core: accumulate g rows over edge range [beg,end)
__device__ __forceinline__ void gath(const unsigned int* __restrict__ csr,
                                     const uint2* __restrict__ g2, int j,
                                     int beg, int end,
                                     float& c0, float& c1, float& c2, float& c3) {
    int e = beg;
    for (; e + 8 <= end; e += 8) {
        int s0 = (int)csr[e + 0], s1 = (int)csr[e + 1];
        int s2 = (int)csr[e + 2], s3 = (int)csr[e + 3];
        int s4 = (int)csr[e + 4], s5 = (int)csr[e + 5];
        int s6 = (int)csr[e + 6], s7 = (int)csr[e + 7];
        uint2 r0 = g2[s0 * 8 + j];
        uint2 r1 = g2[s1 * 8 + j];
        uint2 r2 = g2[s2 * 8 + j];
        uint2 r3 = g2[s3 * 8 + j];
        uint2 r4 = g2[s4 * 8 + j];
        uint2 r5 = g2[s5 * 8 + j];
        uint2 r6 = g2[s6 * 8 + j];
        uint2 r7 = g2[s7 * 8 + j];
        acc4(c0, c1, c2, c3, r0);
        acc4(c0, c1, c2, c3, r1);
        acc4(c0, c1, c2, c3, r2);
        acc4(c0, c1, c2, c3, r3);
        acc4(c0, c1, c2, c3, r4);
        acc4(c0, c1, c2, c3, r5);
        acc4(c0, c1, c2, c3, r6);
        acc4(c0, c1, c2, c3, r7);
    }
    for (; e < end; e++) {
        int s = (int)csr[e];
        uint2 r = g2[s * 8 + j];
        acc4(c0, c1, c2, c3, r);
    }
}

// ---- layer 2 pass A: gather src-half-0 edges only (3.2MB window, L2-resident);
// write raw fp32 partial sums, nontemporal (pure stream, keep L2 for the window)
__global__ void k_l2a(const unsigned int* __restrict__ csr, const int* __restrict__ rowptr,
                      const int* __restrict__ qmid, const __half* __restrict__ g,
                      fvec4* __restrict__ part4, int N) {
    int t = blockIdx.x * blockDim.x + threadIdx.x;
    int i = t >> 3, j = t & 7;
    if (i >= N) return;
    float c0 = 0.f, c1 = 0.f, c2 = 0.f, c3 = 0.f;
    gath(csr, (const uint2*)g, j, rowptr[i], qmid[i], c0, c1, c2, c3);
    fvec4 p = {c0, c1, c2, c3};
    __builtin_nontemporal_store(p, &part4[(size_t)i * 8 + j]);
}

// ---- layer 2 pass B: gather src-half-1 edges, add partials + self row,
// di scale, W2/W3 epilogue (lane j -> outputs 4j..4j+3), q write.
__global__ void k_l2b(const unsigned int* __restrict__ csr, const int* __restrict__ rowptr,
                      const int* __restrict__ qmid, const __half* __restrict__ g,
                      const float* __restrict__ dis, const fvec4* __restrict__ part4,
                      const float* __restrict__ W2, const float* __restrict__ b2,
                      const float* __restrict__ W3, float* __restrict__ q, int N) {
    int t = blockIdx.x * blockDim.x + threadIdx.x;
    int i = t >> 3, j = t & 7;
    if (i >= N) return;
    const uint2* g2 = (const uint2*)g;
    float c0 = 0.f, c1 = 0.f, c2 = 0.f, c3 = 0.f;
    gath(csr, g2, j, qmid[i], rowptr[i + 1], c0, c1, c2, c3);
    fvec4 p = __builtin_nontemporal_load(&part4[(size_t)i * 8 + j]);
    c0 += p.x; c1 += p.y; c2 += p.z; c3 += p.w;
    float di = dis[i];
    uint2 rs = g2[i * 8 + j];                        // self-loop slice
    float2 sa = __half22float2(*(const __half2*)&rs.x);
    float2 sb = __half22float2(*(const __half2*)&rs.y);
    float a0 = di * (c0 + sa.x);
    float a1 = di * (c1 + sa.y);
    float a2 = di * (c2 + sb.x);
    float a3 = di * (c3 + sb.y);
    int m = 4 * j;
    float o0 = b2[m + 0], o1 = b2[m + 1], o2 = b2[m + 2], o3 = b2[m + 3];
#pragma unroll
    for (int kl = 0; kl < 8; kl++) {
        float x0 = __shfl(a0, kl, 8);                // a[4kl+0]
        float x1 = __shfl(a1, kl, 8);
        float x2 = __shfl(a2, kl, 8);
        float x3 = __shfl(a3, kl, 8);
        const float* w0 = W2 + (4 * kl) * 32 + m;    // rows 4kl..4kl+3, cols m..m+3
        o0 = fmaf(x0, w0[0], fmaf(x1, w0[32], fmaf(x2, w0[64], fmaf(x3, w0[96], o0))));
        o1 = fmaf(x0, w0[1], fmaf(x1, w0[33], fmaf(x2, w0[65], fmaf(x3, w0[97], o1))));
        o2 = fmaf(x0, w0[2], fmaf(x1, w0[34], fmaf(x2, w0[66], fmaf(x3, w0[98], o2))));
        o3 = fmaf(x0, w0[3], fmaf(x1, w0[35], fmaf(x2, w0[67], fmaf(x3, w0[99], o3))));
    }
    float cc = fmaxf(o0, 0.f) * W3[m + 0] + fmaxf(o1, 0.f) * W3[m + 1]
             + fmaxf(o2, 0.f) * W3[m + 2] + fmaxf(o3, 0.f) * W3[m + 3];
    cc += __shfl_xor(cc, 1, 8);
    cc += __shfl_xor(cc, 2, 8);
    cc += __shfl_xor(cc, 4, 8);
    if (j == 0) q[i] = di * cc;                      // q = dis * p
}

// ---- fallback single-pass layer 2 (R11) if ws can't hold part/qmid
__global__ void k_l2f(const unsigned int* __restrict__ csr, const int* __restrict__ rowptr,
                      const __half* __restrict__ g, const float* __restrict__ dis,
                      const float* __restrict__ W2, const float* __restrict__ b2,
                      const float* __restrict__ W3, float* __restrict__ q, int N) {
    int t = blockIdx.x * blockDim.x + threadIdx.x;
    int i = t >> 3, j = t & 7;
    if (i >= N) return;
    const uint2* g2 = (const uint2*)g;
    float c0 = 0.f, c1 = 0.f, c2 = 0.f, c3 = 0.f;
    gath(csr, g2, j, rowptr[i], rowptr[i + 1], c0, c1, c2, c3);
    float di = dis[i];
    uint2 rs = g2[i * 8 + j];
    float2 sa = __half22float2(*(const __half2*)&rs.x);
    float2 sb = __half22float2(*(const __half2*)&rs.y);
    float a0 = di * (c0 + sa.x);
    float a1 = di * (c1 + sa.y);
    float a2 = di * (c2 + sb.x);
    float a3 = di * (c3 + sb.y);
    int m = 4 * j;
    float o0 = b2[m + 0], o1 = b2[m + 1], o2 = b2[m + 2], o3 = b2[m + 3];
#pragma unroll
    for (int kl = 0; kl < 8; kl++) {
        float x0 = __shfl(a0, kl, 8);
        float x1 = __shfl(a1, kl, 8);
        float x2 = __shfl(a2, kl, 8);
        float x3 = __shfl(a3, kl, 8);
        const float* w0 = W2 + (4 * kl) * 32 + m;
        o0 = fmaf(x0, w0[0], fmaf(x1, w0[32], fmaf(x2, w0[64], fmaf(x3, w0[96], o0))));
        o1 = fmaf(x0, w0[1], fmaf(x1, w0[33], fmaf(x2, w0[65], fmaf(x3, w0[97], o1))));
        o2 = fmaf(x0, w0[2], fmaf(x1, w0[34], fmaf(x2, w0[66], fmaf(x3, w0[98], o2))));
        o3 = fmaf(x0, w0[3], fmaf(x1, w0[35], fmaf(x2, w0[67], fmaf(x3, w0[99], o3))));
    }
    float cc = fmaxf(o0, 0.f) * W3[m + 0] + fmaxf(o1, 0.f) * W3[m + 1]
             + fmaxf(o2, 0.f) * W3[m + 2] + fmaxf(o3, 0.f) * W3[m + 3];
    cc += __shfl_xor(cc, 1, 8);
    cc += __shfl_xor(cc, 2, 8);
    cc += __shfl_xor(cc, 4, 8);
    if (j == 0) q[i] = di * cc;
}

// ---- layer 3: node-parallel scalar q gathers (q 400KB, L2-resident)
__global__ void k_l3(const unsigned int* __restrict__ csr, const int* __restrict__ rowptr,
                     const float* __restrict__ q, const float* __restrict__ dis,
                     const float* __restrict__ b3, float* __restrict__ out, int N) {
    int t = blockIdx.x * blockDim.x + threadIdx.x;
    int i = t >> 5, j = t & 31;
    if (i >= N) return;
    int beg = rowptr[i], end = rowptr[i + 1];
    float acc = 0.f;
    for (int e = beg + j; e < end; e += 32)
        acc += q[csr[e]];
#pragma unroll
    for (int m = 16; m >= 1; m >>= 1)
        acc += __shfl_xor(acc, m, 32);
    if (j == 0) out[i] = dis[i] * (acc + q[i]) + b3[0];
}

extern "C" void kernel_launch(void* const* d_in, const int* in_sizes, int n_in,
                              void* d_out, int out_size, void* d_ws, size_t ws_size,
                              hipStream_t stream) {
    const float* x  = (const float*)d_in[0];
    const int*   ei = (const int*)d_in[1];
    const float* W1 = (const float*)d_in[2];
    const float* b1 = (const float*)d_in[3];
    const float* W2 = (const float*)d_in[4];
    const float* b2 = (const float*)d_in[5];
    const float* W3 = (const float*)d_in[6];
    const float* b3 = (const float*)d_in[7];
    float* out = (float*)d_out;

    int N = in_sizes[0] / 3;
    int E = in_sizes[1] / 2;
    const int* src = ei;
    const int* dst = ei + E;

    // workspace (all init done in-kernel; no memset needed), 256B-aligned carves
    char* w = (char*)d_ws;
#define CARVE(nbytes) w; w += (((size_t)(nbytes) + 255) & ~(size_t)255)
    int*   hist   = (int*)  CARVE((size_t)SB * NBKT * 4);   // 4.0 MB
    int*   btot   = (int*)  CARVE((size_t)MAXNB * 4);
    int*   bbase  = (int*)  CARVE((size_t)(MAXNB + 1) * 4);
    int*   rowptr = (int*)  CARVE((size_t)(N + 1) * 4);
    float* dis    = (float*)CARVE((size_t)N * 4);
    float* y4     = (float*)CARVE((size_t)N * 16);
    __half* g     = (__half*)CARVE((size_t)N * 32 * 2);     // 6.4 MB fp16
    float* q      = (float*)CARVE((size_t)N * 4);
    unsigned int* packed = (unsigned int*)CARVE((size_t)E * 4);  // 25.6 MB
    int*   qmid   = (int*)  CARVE((size_t)N * 4);           // split path only
    fvec4* part4  = (fvec4*)CARVE((size_t)N * 32 * 4);      // 12.8 MB, split only
    size_t need_split = (size_t)(w - (char*)d_ws);
#undef CARVE
    int use_split = (ws_size >= need_split);
    if (!use_split) qmid = hist;                  // hist dead after k_bsort; k_sort
                                                  // still needs a valid sink (0.4MB)

    k_hist <<<SB, BLK, 0, stream>>>(dst, hist, E);
    k_scanA<<<NBKT, BLK, 0, stream>>>(hist, btot, NBKT);
    k_scanB<<<1, MAXNB, 0, stream>>>(btot, bbase, NBKT, E);
    k_bsort<<<SB, BLK2, 0, stream>>>(src, dst, hist, btot, bbase, packed, E);
    k_sort <<<NBKT, BLK2, 0, stream>>>(packed, bbase, x, dis, (float4*)y4, rowptr,
                                       qmid, N, E);

    long long tn = (long long)N * 32;
    unsigned gn = (unsigned)((tn + BLK - 1) / BLK);
    long long tn8 = (long long)N * 8;
    unsigned gn8 = (unsigned)((tn8 + BLK - 1) / BLK);
    k_l1<<<gn, BLK, 0, stream>>>(packed, rowptr, (const float4*)y4, dis, W1, b1, g, N);
    if (use_split) {
        k_l2a<<<gn8, BLK, 0, stream>>>(packed, rowptr, qmid, g, part4, N);
        k_l2b<<<gn8, BLK, 0, stream>>>(packed, rowptr, qmid, g, dis, part4,
                                       W2, b2, W3, q, N);
    } else {
        k_l2f<<<gn8, BLK, 0, stream>>>(packed, rowptr, g, dis, W2, b2, W3, q, N);
    }
    k_l3<<<gn, BLK, 0, stream>>>(packed, rowptr, q, dis, b3, out, N);
}

// Round 7
// 332.191 us; speedup vs baseline: 1.0719x; 1.0138x over previous
//
#include <hip/hip_runtime.h>
#include <hip/hip_fp16.h>

// GCN 3->32->32->1, N=100K, E=6.4M (+self loops).
// R11: 8-lane/node single-pass k_l2 = 69.7us (VALU 28%, HBM 35%).
// R12-R13: src-half split k_l2a+b -> FETCH 190->80MB but 92us combined:
//   proves k_l2 per-edge cost is INVARIANT to L2 misses (not miss-bound).
// R14: k_sort/k_bsort 512-thr + fused load-count + BUFSZ 10240 -> off top5.
// R15: (a) revert layer2 to single pass (drop part/qmid round-trip and
//   half-binning: ~-22us structural); (b) attack the real k_l2 bound —
//   the 8-deep dependent add chain into one accumulator set — with 4
//   register banks (chain depth 8->2/iter, +12 VGPR). Locality work
//   intentionally abandoned (proven irrelevant by the split experiment).
// Carried: fp16 g table, fused k_sort, node-parallel layers, zero global
//   atomics, 256B-aligned carves, hist-row-differencing k_bsort.

#define BLK 256
#define BLK2 512         // k_bsort / k_sort block size
#define SB 1280          // chunks; SB*CHUNK == E exactly
#define CHUNK 5000
#define BKT 128          // nodes per bucket
#define NBKT 782         // ceil(100000/128)
#define MAXNB 1024       // scanB width >= NBKT
#define BUFSZ 10240      // k_sort bucket buffer (mean 8192 + 22 sigma)

// ---- pass 1: per-chunk histogram over dst buckets (LDS, int4 loads)
__global__ void k_hist(const int* __restrict__ dst, int* __restrict__ hist, int E) {
    __shared__ int lh[NBKT];
    for (int b = threadIdx.x; b < NBKT; b += blockDim.x) lh[b] = 0;
    __syncthreads();
    int beg = blockIdx.x * CHUNK;
    int end = min(E, beg + CHUNK);
    int nq = (end - beg) >> 2;                    // full int4 quads
    const int4* d4 = (const int4*)(dst + beg);
    for (int i = threadIdx.x; i < nq; i += blockDim.x) {
        int4 d = d4[i];
        atomicAdd(&lh[d.x >> 7], 1);
        atomicAdd(&lh[d.y >> 7], 1);
        atomicAdd(&lh[d.z >> 7], 1);
        atomicAdd(&lh[d.w >> 7], 1);
    }
    for (int e = beg + (nq << 2) + threadIdx.x; e < end; e += blockDim.x)
        atomicAdd(&lh[dst[e] >> 7], 1);
    __syncthreads();
    for (int b = threadIdx.x; b < NBKT; b += blockDim.x)
        hist[(size_t)blockIdx.x * NBKT + b] = lh[b];
}

// ---- scan A: per bucket, exclusive-scan its SB chunk-counts (shfl, 5 items/thr)
__global__ void k_scanA(int* __restrict__ hist, int* __restrict__ btot, int NB) {
    int b = blockIdx.x, t = threadIdx.x;          // 256 threads * 5 items = 1280
    int base = t * 5;
    int v0 = hist[(size_t)(base + 0) * NB + b];
    int v1 = hist[(size_t)(base + 1) * NB + b];
    int v2 = hist[(size_t)(base + 2) * NB + b];
    int v3 = hist[(size_t)(base + 3) * NB + b];
    int v4 = hist[(size_t)(base + 4) * NB + b];
    int s = v0 + v1 + v2 + v3 + v4;
    int lane = t & 63, w = t >> 6;
    int x = s;
#pragma unroll
    for (int off = 1; off < 64; off <<= 1) {
        int u = __shfl_up(x, off, 64);
        if (lane >= off) x += u;
    }
    __shared__ int wsum[4];
    if (lane == 63) wsum[w] = x;
    __syncthreads();
    int woff = 0;
    for (int k = 0; k < 4; k++) woff += (k < w) ? wsum[k] : 0;
    int run = woff + x - s;                       // exclusive prefix for item 0
    hist[(size_t)(base + 0) * NB + b] = run;  run += v0;
    hist[(size_t)(base + 1) * NB + b] = run;  run += v1;
    hist[(size_t)(base + 2) * NB + b] = run;  run += v2;
    hist[(size_t)(base + 3) * NB + b] = run;  run += v3;
    hist[(size_t)(base + 4) * NB + b] = run;  run += v4;
    if (t == 255) btot[b] = run;
}

// ---- scan B: exclusive-scan bucket totals -> bucket base offsets
__global__ void k_scanB(const int* __restrict__ btot, int* __restrict__ bbase,
                        int NB, int E) {
    __shared__ int sh[MAXNB];
    int t = threadIdx.x;
    int v = (t < NB) ? btot[t] : 0;
    sh[t] = v;
    __syncthreads();
    for (int off = 1; off < MAXNB; off <<= 1) {
        int u = (t >= off) ? sh[t - off] : 0;
        __syncthreads();
        sh[t] += u;
        __syncthreads();
    }
    if (t < NB) bbase[t] = sh[t] - v;
    if (t == 0) bbase[NB] = E;
}

// ---- pass 2: LDS chunk-sort by bucket, full-lane sorted-order streaming.
// Chunk counts from hist-row differencing (scanA in-place prefixes).
__global__ void k_bsort(const int* __restrict__ src, const int* __restrict__ dst,
                        const int* __restrict__ hist, const int* __restrict__ btot,
                        const int* __restrict__ bbase,
                        unsigned int* __restrict__ packed, int E) {
    __shared__ unsigned int bufB[CHUNK];          // 20 KB
    __shared__ unsigned short binarr2[CHUNK];     // 10 KB (bucket of sorted pos)
    __shared__ int cnt[NBKT];
    __shared__ int off[NBKT];
    __shared__ int cur[NBKT];
    __shared__ int gbase[NBKT];
    __shared__ int wsum[8];
    int t = threadIdx.x;
    int beg = blockIdx.x * CHUNK;
    int end = min(E, beg + CHUNK);
    int len = end - beg;
    int last = (blockIdx.x + 1 == gridDim.x);
    for (int b = t; b < NBKT; b += blockDim.x) {
        int my = hist[(size_t)blockIdx.x * NBKT + b];
        int nx = last ? btot[b] : hist[(size_t)(blockIdx.x + 1) * NBKT + b];
        cnt[b] = nx - my;
        gbase[b] = bbase[b] + my;
    }
    __syncthreads();
    // phase b: exclusive scan of 782 counts (2 items/thread, shfl, 8 waves)
    {
        int base = t * 2;
        int v0 = (base + 0 < NBKT) ? cnt[base + 0] : 0;
        int v1 = (base + 1 < NBKT) ? cnt[base + 1] : 0;
        int s = v0 + v1;
        int lane = t & 63, w = t >> 6;
        int x = s;
#pragma unroll
        for (int o = 1; o < 64; o <<= 1) {
            int u = __shfl_up(x, o, 64);
            if (lane >= o) x += u;
        }
        if (lane == 63) wsum[w] = x;
        __syncthreads();
        int woff = 0;
        for (int k = 0; k < 8; k++) woff += (k < w) ? wsum[k] : 0;
        int run = woff + x - s;
        if (base + 0 < NBKT) { off[base + 0] = run; cur[base + 0] = run; } run += v0;
        if (base + 1 < NBKT) { off[base + 1] = run; cur[base + 1] = run; } run += v1;
    }
    __syncthreads();
    // phase c: permute into bucket-grouped order
    for (int i = t; i < len; i += blockDim.x) {
        int d = dst[beg + i];
        int s = src[beg + i];
        int b = d >> 7;
        int pos = atomicAdd(&cur[b], 1);
        bufB[pos] = (unsigned)s | ((unsigned)(d & 127) << 17);
        binarr2[pos] = (unsigned short)b;
    }
    __syncthreads();
    // phase d: full-lane sorted-order write (runs are dest-contiguous)
    for (int i = t; i < len; i += blockDim.x) {
        int b = binarr2[i];
        packed[gbase[b] + i - off[b]] = bufB[i];
    }
}

// ---- fused: per-bucket 128-bin count + scan + dis/y4/rowptr + in-place
// node sort. 512 threads, fused load+count.
__global__ void k_sort(unsigned int* __restrict__ packed, const int* __restrict__ bbase,
                       const float* __restrict__ x, float* __restrict__ dis,
                       float4* __restrict__ y4, int* __restrict__ rowptr, int N, int E) {
    __shared__ unsigned int buf[BUFSZ];           // 40 KB
    __shared__ int cnt[BKT];
    __shared__ int cur[BKT];
    __shared__ int wsum[2];
    int b = blockIdx.x, t = threadIdx.x;
    int beg = bbase[b], end = bbase[b + 1];
    int len = end - beg;
    if (t < BKT) cnt[t] = 0;
    __syncthreads();
    // fused: load bucket into LDS + count bins in one pass
    for (int i = t; i < len; i += blockDim.x) {
        unsigned v = packed[beg + i];
        buf[i] = v;
        atomicAdd(&cnt[v >> 17], 1);
    }
    __syncthreads();
    // exclusive scan over 128 bins (threads 0..127, 2 waves)
    int v0 = 0, xs = 0;
    if (t < BKT) {
        v0 = cnt[t];
        xs = v0;
#pragma unroll
        for (int o = 1; o < 64; o <<= 1) {
            int u = __shfl_up(xs, o, 64);
            if ((t & 63) >= o) xs += u;
        }
        if ((t & 63) == 63) wsum[t >> 6] = xs;
    }
    __syncthreads();
    if (t < BKT) {
        int woff = (t >= 64) ? wsum[0] : 0;
        int excl = woff + xs - v0;
        cur[t] = excl;
        int gi = b * BKT + t;
        if (gi < N) {
            rowptr[gi] = beg + excl;
            float di = rsqrtf((float)v0 + 1.0f);  // + self loop
            dis[gi] = di;
            float4 y;
            y.x = di * x[3 * gi + 0];
            y.y = di * x[3 * gi + 1];
            y.z = di * x[3 * gi + 2];
            y.w = 0.0f;
            y4[gi] = y;
        }
    }
    __syncthreads();
    for (int i = t; i < len; i += blockDim.x) {
        unsigned vv = buf[i];
        int pos = atomicAdd(&cur[vv >> 17], 1);   // LDS atomic
        packed[beg + pos] = vv & 0x1FFFF;         // plain src id, node-sorted
    }
    if (b == 0 && t == 0) rowptr[N] = E;
}

// ---- layer 1: node-parallel, 32 lanes/node gather y4 (1.6MB, L2-resident)
__global__ void k_l1(const unsigned int* __restrict__ csr, const int* __restrict__ rowptr,
                     const float4* __restrict__ y4, const float* __restrict__ dis,
                     const float* __restrict__ W1, const float* __restrict__ b1,
                     __half* __restrict__ g, int N) {
    int t = blockIdx.x * blockDim.x + threadIdx.x;
    int i = t >> 5, j = t & 31;
    if (i >= N) return;
    int beg = rowptr[i], end = rowptr[i + 1];
    float ax = 0.f, ay = 0.f, az = 0.f;
    for (int e = beg + j; e < end; e += 32) {
        float4 yv = y4[csr[e]];
        ax += yv.x; ay += yv.y; az += yv.z;
    }
#pragma unroll
    for (int m = 16; m >= 1; m >>= 1) {
        ax += __shfl_xor(ax, m, 32);
        ay += __shfl_xor(ay, m, 32);
        az += __shfl_xor(az, m, 32);
    }
    float di = dis[i];
    float4 ys = y4[i];                               // self loop (pre-scaled)
    float a0 = di * (ax + ys.x);
    float a1 = di * (ay + ys.y);
    float a2 = di * (az + ys.z);
    float h = b1[j] + a0 * W1[j] + a1 * W1[32 + j] + a2 * W1[64 + j];
    g[(size_t)i * 32 + j] = __float2half(di * fmaxf(h, 0.f));
}

// unpack one uint2 (4 halves) and accumulate into 4 fp32 accumulators
__device__ __forceinline__ void acc4(float& c0, float& c1, float& c2, float& c3,
                                     uint2 r) {
    __half2 a = *(const __half2*)&r.x;
    __half2 b = *(const __half2*)&r.y;
    float2 fa = __half22float2(a);
    float2 fb = __half22float2(b);
    c0 += fa.x; c1 += fa.y; c2 += fb.x; c3 += fb.y;
}

// ---- layer 2 (+L3 projection): 8 lanes/node, lane j owns features 4j..4j+3.
// Per edge: broadcast csr load + one 8B dwordx2 gather (8 lanes = full 64B
// row, line-coalesced) + 4 cvt/add. 8-edge unroll into FOUR accumulator
// banks (dependent-add chain depth 8 -> 2 per iteration).
__global__ void k_l2(const unsigned int* __restrict__ csr, const int* __restrict__ rowptr,
                     const __half* __restrict__ g, const float* __restrict__ dis,
                     const float* __restrict__ W2, const float* __restrict__ b2,
                     const float* __restrict__ W3, float* __restrict__ q, int N) {
    int t = blockIdx.x * blockDim.x + threadIdx.x;
    int i = t >> 3, j = t & 7;
    if (i >= N) return;
    int beg = rowptr[i], end = rowptr[i + 1];
    const uint2* g2 = (const uint2*)g;               // [N][8] x 8B slices
    float pa0 = 0.f, pa1 = 0.f, pa2 = 0.f, pa3 = 0.f;   // bank A
    float pb0 = 0.f, pb1 = 0.f, pb2 = 0.f, pb3 = 0.f;   // bank B
    float pc0 = 0.f, pc1 = 0.f, pc2 = 0.f, pc3 = 0.f;   // bank C
    float pd0 = 0.f, pd1 = 0.f, pd2 = 0.f, pd3 = 0.f;   // bank D
    int e = beg;
    for (; e + 8 <= end; e += 8) {
        int s0 = (int)csr[e + 0], s1 = (int)csr[e + 1];
        int s2 = (int)csr[e + 2], s3 = (int)csr[e + 3];
        int s4 = (int)csr[e + 4], s5 = (int)csr[e + 5];
        int s6 = (int)csr[e + 6], s7 = (int)csr[e + 7];
        uint2 r0 = g2[s0 * 8 + j];
        uint2 r1 = g2[s1 * 8 + j];
        uint2 r2 = g2[s2 * 8 + j];
        uint2 r3 = g2[s3 * 8 + j];
        uint2 r4 = g2[s4 * 8 + j];
        uint2 r5 = g2[s5 * 8 + j];
        uint2 r6 = g2[s6 * 8 + j];
        uint2 r7 = g2[s7 * 8 + j];
        acc4(pa0, pa1, pa2, pa3, r0);
        acc4(pb0, pb1, pb2, pb3, r1);
        acc4(pc0, pc1, pc2, pc3, r2);
        acc4(pd0, pd1, pd2, pd3, r3);
        acc4(pa0, pa1, pa2, pa3, r4);
        acc4(pb0, pb1, pb2, pb3, r5);
        acc4(pc0, pc1, pc2, pc3, r6);
        acc4(pd0, pd1, pd2, pd3, r7);
    }
    for (; e < end; e++) {
        int s = (int)csr[e];
        uint2 r = g2[s * 8 + j];
        acc4(pa0, pa1, pa2, pa3, r);
    }
    float c0 = (pa0 + pb0) + (pc0 + pd0);
    float c1 = (pa1 + pb1) + (pc1 + pd1);
    float c2 = (pa2 + pb2) + (pc2 + pd2);
    float c3 = (pa3 + pb3) + (pc3 + pd3);
    float di = dis[i];
    uint2 rs = g2[i * 8 + j];                        // self-loop slice
    float2 sa = __half22float2(*(const __half2*)&rs.x);
    float2 sb = __half22float2(*(const __half2*)&rs.y);
    float a0 = di * (c0 + sa.x);
    float a1 = di * (c1 + sa.y);
    float a2 = di * (c2 + sb.x);
    float a3 = di * (c3 + sb.y);
    // W2 matmul: lane j -> outputs m=4j..4j+3 (W2 is [32 in][32 out] row-major)
    int m = 4 * j;
    float o0 = b2[m + 0], o1 = b2[m + 1], o2 = b2[m + 2], o3 = b2[m + 3];
#pragma unroll
    for (int kl = 0; kl < 8; kl++) {
        float x0 = __shfl(a0, kl, 8);                // a[4kl+0]
        float x1 = __shfl(a1, kl, 8);
        float x2 = __shfl(a2, kl, 8);
        float x3 = __shfl(a3, kl, 8);
        const float* w0 = W2 + (4 * kl) * 32 + m;    // rows 4kl..4kl+3, cols m..m+3
        o0 = fmaf(x0, w0[0], fmaf(x1, w0[32], fmaf(x2, w0[64], fmaf(x3, w0[96], o0))));
        o1 = fmaf(x0, w0[1], fmaf(x1, w0[33], fmaf(x2, w0[65], fmaf(x3, w0[97], o1))));
        o2 = fmaf(x0, w0[2], fmaf(x1, w0[34], fmaf(x2, w0[66], fmaf(x3, w0[98], o2))));
        o3 = fmaf(x0, w0[3], fmaf(x1, w0[35], fmaf(x2, w0[67], fmaf(x3, w0[99], o3))));
    }
    float cc = fmaxf(o0, 0.f) * W3[m + 0] + fmaxf(o1, 0.f) * W3[m + 1]
             + fmaxf(o2, 0.f) * W3[m + 2] + fmaxf(o3, 0.f) * W3[m + 3];
    cc += __shfl_xor(cc, 1, 8);
    cc += __shfl_xor(cc, 2, 8);
    cc += __shfl_xor(cc, 4, 8);
    if (j == 0) q[i] = di * cc;                      // q = dis * p
}

// ---- layer 3: node-parallel scalar q gathers (q 400KB, L2-resident)
__global__ void k_l3(const unsigned int* __restrict__ csr, const int* __restrict__ rowptr,
                     const float* __restrict__ q, const float* __restrict__ dis,
                     const float* __restrict__ b3, float* __restrict__ out, int N) {
    int t = blockIdx.x * blockDim.x + threadIdx.x;
    int i = t >> 5, j = t & 31;
    if (i >= N) return;
    int beg = rowptr[i], end = rowptr[i + 1];
    float acc = 0.f;
    for (int e = beg + j; e < end; e += 32)
        acc += q[csr[e]];
#pragma unroll
    for (int m = 16; m >= 1; m >>= 1)
        acc += __shfl_xor(acc, m, 32);
    if (j == 0) out[i] = dis[i] * (acc + q[i]) + b3[0];
}

extern "C" void kernel_launch(void* const* d_in, const int* in_sizes, int n_in,
                              void* d_out, int out_size, void* d_ws, size_t ws_size,
                              hipStream_t stream) {
    const float* x  = (const float*)d_in[0];
    const int*   ei = (const int*)d_in[1];
    const float* W1 = (const float*)d_in[2];
    const float* b1 = (const float*)d_in[3];
    const float* W2 = (const float*)d_in[4];
    const float* b2 = (const float*)d_in[5];
    const float* W3 = (const float*)d_in[6];
    const float* b3 = (const float*)d_in[7];
    float* out = (float*)d_out;

    int N = in_sizes[0] / 3;
    int E = in_sizes[1] / 2;
    const int* src = ei;
    const int* dst = ei + E;

    // workspace (all init done in-kernel; no memset needed), 256B-aligned carves
    char* w = (char*)d_ws;
#define CARVE(nbytes) w; w += (((size_t)(nbytes) + 255) & ~(size_t)255)
    int*   hist   = (int*)  CARVE((size_t)SB * NBKT * 4);   // 4.0 MB
    int*   btot   = (int*)  CARVE((size_t)MAXNB * 4);
    int*   bbase  = (int*)  CARVE((size_t)(MAXNB + 1) * 4);
    int*   rowptr = (int*)  CARVE((size_t)(N + 1) * 4);
    float* dis    = (float*)CARVE((size_t)N * 4);
    float* y4     = (float*)CARVE((size_t)N * 16);
    __half* g     = (__half*)CARVE((size_t)N * 32 * 2);     // 6.4 MB fp16
    float* q      = (float*)CARVE((size_t)N * 4);
    unsigned int* packed = (unsigned int*)CARVE((size_t)E * 4);  // 25.6 MB
#undef CARVE

    k_hist <<<SB, BLK, 0, stream>>>(dst, hist, E);
    k_scanA<<<NBKT, BLK, 0, stream>>>(hist, btot, NBKT);
    k_scanB<<<1, MAXNB, 0, stream>>>(btot, bbase, NBKT, E);
    k_bsort<<<SB, BLK2, 0, stream>>>(src, dst, hist, btot, bbase, packed, E);
    k_sort <<<NBKT, BLK2, 0, stream>>>(packed, bbase, x, dis, (float4*)y4, rowptr, N, E);

    long long tn = (long long)N * 32;
    unsigned gn = (unsigned)((tn + BLK - 1) / BLK);
    long long tn8 = (long long)N * 8;
    unsigned gn8 = (unsigned)((tn8 + BLK - 1) / BLK);
    k_l1<<<gn,  BLK, 0, stream>>>(packed, rowptr, (const float4*)y4, dis, W1, b1, g, N);
    k_l2<<<gn8, BLK, 0, stream>>>(packed, rowptr, g, dis, W2, b2, W3, q, N);
    k_l3<<<gn,  BLK, 0, stream>>>(packed, rowptr, q, dis, b3, out, N);
}

// Round 8
// 326.761 us; speedup vs baseline: 1.0897x; 1.0166x over previous
//
#include <hip/hip_runtime.h>
#include <hip/hip_fp16.h>

// GCN 3->32->32->1, N=100K, E=6.4M (+self loops).
// R11-R15 synthesis: k_l2 cost is ~11-14ns per gathered 64B line, invariant
//   to L2/HBM hit mix (R12 split: half lines/pass -> ~half time; R10
//   feature split: same lines/pass -> same time; R15 4-bank acc: no change).
//   => bound is the per-CU vector-memory miss path (~6-7 cyc/line-miss),
//   not VALU, not HBM bytes, not dep chains.
// R16: strip all VMEM that is NOT the unavoidable 1-line-per-edge gather:
//   (a) csr loads: 8 redundant scalar/iter -> 2x int4 per lane (head-peel
//       to 4-alignment), VMEM instrs per 8-edge iter 16 -> 10;
//   (b) epilogue W2: 128 scalar VMEM loads/thread (102M lane-loads!) ->
//       LDS-staged W2/b2/W3 (4.25KB/block), 32x ds_read_b128, zero VMEM.
//   Discriminating experiment: no change => 1-miss/edge floor (~67us)
//   confirmed hard, pivot.
// Carried: fp16 g table, 8-lane/node gathers, 4 acc banks, fused k_sort,
//   node-parallel layers, zero global atomics, 256B-aligned carves.

#define BLK 256
#define BLK2 512         // k_bsort / k_sort block size
#define SB 1280          // chunks; SB*CHUNK == E exactly
#define CHUNK 5000
#define BKT 128          // nodes per bucket
#define NBKT 782         // ceil(100000/128)
#define MAXNB 1024       // scanB width >= NBKT
#define BUFSZ 10240      // k_sort bucket buffer (mean 8192 + 22 sigma)

// ---- pass 1: per-chunk histogram over dst buckets (LDS, int4 loads)
__global__ void k_hist(const int* __restrict__ dst, int* __restrict__ hist, int E) {
    __shared__ int lh[NBKT];
    for (int b = threadIdx.x; b < NBKT; b += blockDim.x) lh[b] = 0;
    __syncthreads();
    int beg = blockIdx.x * CHUNK;
    int end = min(E, beg + CHUNK);
    int nq = (end - beg) >> 2;                    // full int4 quads
    const int4* d4 = (const int4*)(dst + beg);
    for (int i = threadIdx.x; i < nq; i += blockDim.x) {
        int4 d = d4[i];
        atomicAdd(&lh[d.x >> 7], 1);
        atomicAdd(&lh[d.y >> 7], 1);
        atomicAdd(&lh[d.z >> 7], 1);
        atomicAdd(&lh[d.w >> 7], 1);
    }
    for (int e = beg + (nq << 2) + threadIdx.x; e < end; e += blockDim.x)
        atomicAdd(&lh[dst[e] >> 7], 1);
    __syncthreads();
    for (int b = threadIdx.x; b < NBKT; b += blockDim.x)
        hist[(size_t)blockIdx.x * NBKT + b] = lh[b];
}

// ---- scan A: per bucket, exclusive-scan its SB chunk-counts (shfl, 5 items/thr)
__global__ void k_scanA(int* __restrict__ hist, int* __restrict__ btot, int NB) {
    int b = blockIdx.x, t = threadIdx.x;          // 256 threads * 5 items = 1280
    int base = t * 5;
    int v0 = hist[(size_t)(base + 0) * NB + b];
    int v1 = hist[(size_t)(base + 1) * NB + b];
    int v2 = hist[(size_t)(base + 2) * NB + b];
    int v3 = hist[(size_t)(base + 3) * NB + b];
    int v4 = hist[(size_t)(base + 4) * NB + b];
    int s = v0 + v1 + v2 + v3 + v4;
    int lane = t & 63, w = t >> 6;
    int x = s;
#pragma unroll
    for (int off = 1; off < 64; off <<= 1) {
        int u = __shfl_up(x, off, 64);
        if (lane >= off) x += u;
    }
    __shared__ int wsum[4];
    if (lane == 63) wsum[w] = x;
    __syncthreads();
    int woff = 0;
    for (int k = 0; k < 4; k++) woff += (k < w) ? wsum[k] : 0;
    int run = woff + x - s;                       // exclusive prefix for item 0
    hist[(size_t)(base + 0) * NB + b] = run;  run += v0;
    hist[(size_t)(base + 1) * NB + b] = run;  run += v1;
    hist[(size_t)(base + 2) * NB + b] = run;  run += v2;
    hist[(size_t)(base + 3) * NB + b] = run;  run += v3;
    hist[(size_t)(base + 4) * NB + b] = run;  run += v4;
    if (t == 255) btot[b] = run;
}

// ---- scan B: exclusive-scan bucket totals -> bucket base offsets
__global__ void k_scanB(const int* __restrict__ btot, int* __restrict__ bbase,
                        int NB, int E) {
    __shared__ int sh[MAXNB];
    int t = threadIdx.x;
    int v = (t < NB) ? btot[t] : 0;
    sh[t] = v;
    __syncthreads();
    for (int off = 1; off < MAXNB; off <<= 1) {
        int u = (t >= off) ? sh[t - off] : 0;
        __syncthreads();
        sh[t] += u;
        __syncthreads();
    }
    if (t < NB) bbase[t] = sh[t] - v;
    if (t == 0) bbase[NB] = E;
}

// ---- pass 2: LDS chunk-sort by bucket, full-lane sorted-order streaming.
// Chunk counts from hist-row differencing (scanA in-place prefixes).
__global__ void k_bsort(const int* __restrict__ src, const int* __restrict__ dst,
                        const int* __restrict__ hist, const int* __restrict__ btot,
                        const int* __restrict__ bbase,
                        unsigned int* __restrict__ packed, int E) {
    __shared__ unsigned int bufB[CHUNK];          // 20 KB
    __shared__ unsigned short binarr2[CHUNK];     // 10 KB (bucket of sorted pos)
    __shared__ int cnt[NBKT];
    __shared__ int off[NBKT];
    __shared__ int cur[NBKT];
    __shared__ int gbase[NBKT];
    __shared__ int wsum[8];
    int t = threadIdx.x;
    int beg = blockIdx.x * CHUNK;
    int end = min(E, beg + CHUNK);
    int len = end - beg;
    int last = (blockIdx.x + 1 == gridDim.x);
    for (int b = t; b < NBKT; b += blockDim.x) {
        int my = hist[(size_t)blockIdx.x * NBKT + b];
        int nx = last ? btot[b] : hist[(size_t)(blockIdx.x + 1) * NBKT + b];
        cnt[b] = nx - my;
        gbase[b] = bbase[b] + my;
    }
    __syncthreads();
    // phase b: exclusive scan of 782 counts (2 items/thread, shfl, 8 waves)
    {
        int base = t * 2;
        int v0 = (base + 0 < NBKT) ? cnt[base + 0] : 0;
        int v1 = (base + 1 < NBKT) ? cnt[base + 1] : 0;
        int s = v0 + v1;
        int lane = t & 63, w = t >> 6;
        int x = s;
#pragma unroll
        for (int o = 1; o < 64; o <<= 1) {
            int u = __shfl_up(x, o, 64);
            if (lane >= o) x += u;
        }
        if (lane == 63) wsum[w] = x;
        __syncthreads();
        int woff = 0;
        for (int k = 0; k < 8; k++) woff += (k < w) ? wsum[k] : 0;
        int run = woff + x - s;
        if (base + 0 < NBKT) { off[base + 0] = run; cur[base + 0] = run; } run += v0;
        if (base + 1 < NBKT) { off[base + 1] = run; cur[base + 1] = run; } run += v1;
    }
    __syncthreads();
    // phase c: permute into bucket-grouped order
    for (int i = t; i < len; i += blockDim.x) {
        int d = dst[beg + i];
        int s = src[beg + i];
        int b = d >> 7;
        int pos = atomicAdd(&cur[b], 1);
        bufB[pos] = (unsigned)s | ((unsigned)(d & 127) << 17);
        binarr2[pos] = (unsigned short)b;
    }
    __syncthreads();
    // phase d: full-lane sorted-order write (runs are dest-contiguous)
    for (int i = t; i < len; i += blockDim.x) {
        int b = binarr2[i];
        packed[gbase[b] + i - off[b]] = bufB[i];
    }
}

// ---- fused: per-bucket 128-bin count + scan + dis/y4/rowptr + in-place
// node sort. 512 threads, fused load+count.
__global__ void k_sort(unsigned int* __restrict__ packed, const int* __restrict__ bbase,
                       const float* __restrict__ x, float* __restrict__ dis,
                       float4* __restrict__ y4, int* __restrict__ rowptr, int N, int E) {
    __shared__ unsigned int buf[BUFSZ];           // 40 KB
    __shared__ int cnt[BKT];
    __shared__ int cur[BKT];
    __shared__ int wsum[2];
    int b = blockIdx.x, t = threadIdx.x;
    int beg = bbase[b], end = bbase[b + 1];
    int len = end - beg;
    if (t < BKT) cnt[t] = 0;
    __syncthreads();
    // fused: load bucket into LDS + count bins in one pass
    for (int i = t; i < len; i += blockDim.x) {
        unsigned v = packed[beg + i];
        buf[i] = v;
        atomicAdd(&cnt[v >> 17], 1);
    }
    __syncthreads();
    // exclusive scan over 128 bins (threads 0..127, 2 waves)
    int v0 = 0, xs = 0;
    if (t < BKT) {
        v0 = cnt[t];
        xs = v0;
#pragma unroll
        for (int o = 1; o < 64; o <<= 1) {
            int u = __shfl_up(xs, o, 64);
            if ((t & 63) >= o) xs += u;
        }
        if ((t & 63) == 63) wsum[t >> 6] = xs;
    }
    __syncthreads();
    if (t < BKT) {
        int woff = (t >= 64) ? wsum[0] : 0;
        int excl = woff + xs - v0;
        cur[t] = excl;
        int gi = b * BKT + t;
        if (gi < N) {
            rowptr[gi] = beg + excl;
            float di = rsqrtf((float)v0 + 1.0f);  // + self loop
            dis[gi] = di;
            float4 y;
            y.x = di * x[3 * gi + 0];
            y.y = di * x[3 * gi + 1];
            y.z = di * x[3 * gi + 2];
            y.w = 0.0f;
            y4[gi] = y;
        }
    }
    __syncthreads();
    for (int i = t; i < len; i += blockDim.x) {
        unsigned vv = buf[i];
        int pos = atomicAdd(&cur[vv >> 17], 1);   // LDS atomic
        packed[beg + pos] = vv & 0x1FFFF;         // plain src id, node-sorted
    }
    if (b == 0 && t == 0) rowptr[N] = E;
}

// ---- layer 1: node-parallel, 32 lanes/node gather y4 (1.6MB, L2-resident)
__global__ void k_l1(const unsigned int* __restrict__ csr, const int* __restrict__ rowptr,
                     const float4* __restrict__ y4, const float* __restrict__ dis,
                     const float* __restrict__ W1, const float* __restrict__ b1,
                     __half* __restrict__ g, int N) {
    int t = blockIdx.x * blockDim.x + threadIdx.x;
    int i = t >> 5, j = t & 31;
    if (i >= N) return;
    int beg = rowptr[i], end = rowptr[i + 1];
    float ax = 0.f, ay = 0.f, az = 0.f;
    for (int e = beg + j; e < end; e += 32) {
        float4 yv = y4[csr[e]];
        ax += yv.x; ay += yv.y; az += yv.z;
    }
#pragma unroll
    for (int m = 16; m >= 1; m >>= 1) {
        ax += __shfl_xor(ax, m, 32);
        ay += __shfl_xor(ay, m, 32);
        az += __shfl_xor(az, m, 32);
    }
    float di = dis[i];
    float4 ys = y4[i];                               // self loop (pre-scaled)
    float a0 = di * (ax + ys.x);
    float a1 = di * (ay + ys.y);
    float a2 = di * (az + ys.z);
    float h = b1[j] + a0 * W1[j] + a1 * W1[32 + j] + a2 * W1[64 + j];
    g[(size_t)i * 32 + j] = __float2half(di * fmaxf(h, 0.f));
}

// unpack one uint2 (4 halves) and accumulate into 4 fp32 accumulators
__device__ __forceinline__ void acc4(float& c0, float& c1, float& c2, float& c3,
                                     uint2 r) {
    __half2 a = *(const __half2*)&r.x;
    __half2 b = *(const __half2*)&r.y;
    float2 fa = __half22float2(a);
    float2 fb = __half22float2(b);
    c0 += fa.x; c1 += fa.y; c2 += fb.x; c3 += fb.y;
}

// ---- layer 2 (+L3 projection): 8 lanes/node, lane j owns features 4j..4j+3.
// Per 8-edge iteration per lane: 2x int4 csr loads (head-peeled to 16B
// alignment) + 8x 8B gathers (8 lanes = full 64B row, line-coalesced).
// 4 accumulator banks. Epilogue reads W2/b2/W3 from LDS (zero VMEM).
__global__ void k_l2(const unsigned int* __restrict__ csr, const int* __restrict__ rowptr,
                     const __half* __restrict__ g, const float* __restrict__ dis,
                     const float* __restrict__ W2, const float* __restrict__ b2,
                     const float* __restrict__ W3, float* __restrict__ q, int N) {
    __shared__ float sW2[1024];                      // 4KB: [32 in][32 out]
    __shared__ float sb2[32];
    __shared__ float sW3[32];
    int tid = threadIdx.x;
    ((float4*)sW2)[tid] = ((const float4*)W2)[tid];  // 256 thr x 16B = 4KB
    if (tid < 32) { sb2[tid] = b2[tid]; sW3[tid] = W3[tid]; }
    __syncthreads();
    int t = blockIdx.x * blockDim.x + tid;
    int i = t >> 3, j = t & 7;
    if (i >= N) return;
    int beg = rowptr[i], end = rowptr[i + 1];
    const uint2* g2 = (const uint2*)g;               // [N][8] x 8B slices
    float pa0 = 0.f, pa1 = 0.f, pa2 = 0.f, pa3 = 0.f;   // bank A
    float pb0 = 0.f, pb1 = 0.f, pb2 = 0.f, pb3 = 0.f;   // bank B
    float pc0 = 0.f, pc1 = 0.f, pc2 = 0.f, pc3 = 0.f;   // bank C
    float pd0 = 0.f, pd1 = 0.f, pd2 = 0.f, pd3 = 0.f;   // bank D
    int e = beg;
    // head-peel to 4-edge (16B) alignment for int4 csr loads
    for (; e < end && (e & 3); e++) {
        int s = (int)csr[e];
        uint2 r = g2[s * 8 + j];
        acc4(pa0, pa1, pa2, pa3, r);
    }
    for (; e + 8 <= end; e += 8) {
        int4 ca = *(const int4*)(csr + e);           // slots 0..3 (aligned)
        int4 cb = *(const int4*)(csr + e + 4);       // slots 4..7
        uint2 r0 = g2[ca.x * 8 + j];
        uint2 r1 = g2[ca.y * 8 + j];
        uint2 r2 = g2[ca.z * 8 + j];
        uint2 r3 = g2[ca.w * 8 + j];
        uint2 r4 = g2[cb.x * 8 + j];
        uint2 r5 = g2[cb.y * 8 + j];
        uint2 r6 = g2[cb.z * 8 + j];
        uint2 r7 = g2[cb.w * 8 + j];
        acc4(pa0, pa1, pa2, pa3, r0);
        acc4(pb0, pb1, pb2, pb3, r1);
        acc4(pc0, pc1, pc2, pc3, r2);
        acc4(pd0, pd1, pd2, pd3, r3);
        acc4(pa0, pa1, pa2, pa3, r4);
        acc4(pb0, pb1, pb2, pb3, r5);
        acc4(pc0, pc1, pc2, pc3, r6);
        acc4(pd0, pd1, pd2, pd3, r7);
    }
    for (; e < end; e++) {
        int s = (int)csr[e];
        uint2 r = g2[s * 8 + j];
        acc4(pa0, pa1, pa2, pa3, r);
    }
    float c0 = (pa0 + pb0) + (pc0 + pd0);
    float c1 = (pa1 + pb1) + (pc1 + pd1);
    float c2 = (pa2 + pb2) + (pc2 + pd2);
    float c3 = (pa3 + pb3) + (pc3 + pd3);
    float di = dis[i];
    uint2 rs = g2[i * 8 + j];                        // self-loop slice
    float2 sa = __half22float2(*(const __half2*)&rs.x);
    float2 sb = __half22float2(*(const __half2*)&rs.y);
    float a0 = di * (c0 + sa.x);
    float a1 = di * (c1 + sa.y);
    float a2 = di * (c2 + sb.x);
    float a3 = di * (c3 + sb.y);
    // W2 matmul from LDS: lane j -> outputs m=4j..4j+3
    int m = 4 * j;
    float4 bo = *(const float4*)&sb2[m];
    float o0 = bo.x, o1 = bo.y, o2 = bo.z, o3 = bo.w;
#pragma unroll
    for (int kl = 0; kl < 8; kl++) {
        float x0 = __shfl(a0, kl, 8);                // a[4kl+0]
        float x1 = __shfl(a1, kl, 8);
        float x2 = __shfl(a2, kl, 8);
        float x3 = __shfl(a3, kl, 8);
        float4 w0 = *(const float4*)&sW2[(4 * kl + 0) * 32 + m];
        float4 w1 = *(const float4*)&sW2[(4 * kl + 1) * 32 + m];
        float4 w2 = *(const float4*)&sW2[(4 * kl + 2) * 32 + m];
        float4 w3 = *(const float4*)&sW2[(4 * kl + 3) * 32 + m];
        o0 = fmaf(x0, w0.x, fmaf(x1, w1.x, fmaf(x2, w2.x, fmaf(x3, w3.x, o0))));
        o1 = fmaf(x0, w0.y, fmaf(x1, w1.y, fmaf(x2, w2.y, fmaf(x3, w3.y, o1))));
        o2 = fmaf(x0, w0.z, fmaf(x1, w1.z, fmaf(x2, w2.z, fmaf(x3, w3.z, o2))));
        o3 = fmaf(x0, w0.w, fmaf(x1, w1.w, fmaf(x2, w2.w, fmaf(x3, w3.w, o3))));
    }
    float4 wv = *(const float4*)&sW3[m];
    float cc = fmaxf(o0, 0.f) * wv.x + fmaxf(o1, 0.f) * wv.y
             + fmaxf(o2, 0.f) * wv.z + fmaxf(o3, 0.f) * wv.w;
    cc += __shfl_xor(cc, 1, 8);
    cc += __shfl_xor(cc, 2, 8);
    cc += __shfl_xor(cc, 4, 8);
    if (j == 0) q[i] = di * cc;                      // q = dis * p
}

// ---- layer 3: node-parallel scalar q gathers (q 400KB, L2-resident)
__global__ void k_l3(const unsigned int* __restrict__ csr, const int* __restrict__ rowptr,
                     const float* __restrict__ q, const float* __restrict__ dis,
                     const float* __restrict__ b3, float* __restrict__ out, int N) {
    int t = blockIdx.x * blockDim.x + threadIdx.x;
    int i = t >> 5, j = t & 31;
    if (i >= N) return;
    int beg = rowptr[i], end = rowptr[i + 1];
    float acc = 0.f;
    for (int e = beg + j; e < end; e += 32)
        acc += q[csr[e]];
#pragma unroll
    for (int m = 16; m >= 1; m >>= 1)
        acc += __shfl_xor(acc, m, 32);
    if (j == 0) out[i] = dis[i] * (acc + q[i]) + b3[0];
}

extern "C" void kernel_launch(void* const* d_in, const int* in_sizes, int n_in,
                              void* d_out, int out_size, void* d_ws, size_t ws_size,
                              hipStream_t stream) {
    const float* x  = (const float*)d_in[0];
    const int*   ei = (const int*)d_in[1];
    const float* W1 = (const float*)d_in[2];
    const float* b1 = (const float*)d_in[3];
    const float* W2 = (const float*)d_in[4];
    const float* b2 = (const float*)d_in[5];
    const float* W3 = (const float*)d_in[6];
    const float* b3 = (const float*)d_in[7];
    float* out = (float*)d_out;

    int N = in_sizes[0] / 3;
    int E = in_sizes[1] / 2;
    const int* src = ei;
    const int* dst = ei + E;

    // workspace (all init done in-kernel; no memset needed), 256B-aligned carves
    char* w = (char*)d_ws;
#define CARVE(nbytes) w; w += (((size_t)(nbytes) + 255) & ~(size_t)255)
    int*   hist   = (int*)  CARVE((size_t)SB * NBKT * 4);   // 4.0 MB
    int*   btot   = (int*)  CARVE((size_t)MAXNB * 4);
    int*   bbase  = (int*)  CARVE((size_t)(MAXNB + 1) * 4);
    int*   rowptr = (int*)  CARVE((size_t)(N + 1) * 4);
    float* dis    = (float*)CARVE((size_t)N * 4);
    float* y4     = (float*)CARVE((size_t)N * 16);
    __half* g     = (__half*)CARVE((size_t)N * 32 * 2);     // 6.4 MB fp16
    float* q      = (float*)CARVE((size_t)N * 4);
    unsigned int* packed = (unsigned int*)CARVE((size_t)E * 4);  // 25.6 MB
#undef CARVE

    k_hist <<<SB, BLK, 0, stream>>>(dst, hist, E);
    k_scanA<<<NBKT, BLK, 0, stream>>>(hist, btot, NBKT);
    k_scanB<<<1, MAXNB, 0, stream>>>(btot, bbase, NBKT, E);
    k_bsort<<<SB, BLK2, 0, stream>>>(src, dst, hist, btot, bbase, packed, E);
    k_sort <<<NBKT, BLK2, 0, stream>>>(packed, bbase, x, dis, (float4*)y4, rowptr, N, E);

    long long tn = (long long)N * 32;
    unsigned gn = (unsigned)((tn + BLK - 1) / BLK);
    long long tn8 = (long long)N * 8;
    unsigned gn8 = (unsigned)((tn8 + BLK - 1) / BLK);
    k_l1<<<gn,  BLK, 0, stream>>>(packed, rowptr, (const float4*)y4, dis, W1, b1, g, N);
    k_l2<<<gn8, BLK, 0, stream>>>(packed, rowptr, g, dis, W2, b2, W3, q, N);
    k_l3<<<gn,  BLK, 0, stream>>>(packed, rowptr, q, dis, b3, out, N);
}